// Round 1
// baseline (424.107 us; speedup 1.0000x reference)
//
#include <hip/hip_runtime.h>
#include <hip/hip_bf16.h>

typedef unsigned short u16;
typedef __attribute__((ext_vector_type(8))) short bf16x8;
typedef __attribute__((ext_vector_type(4))) float f32x4;

#define D_MODEL 1024
#define SEQ 2048
#define HEADS 16
#define DK 64
#define BATCH 2
#define MROWS (BATCH * SEQ)   // 4096

__device__ __forceinline__ u16 f2bf(float f) {
    union { float f; unsigned u; } x; x.f = f;
    unsigned r = x.u + 0x7fffu + ((x.u >> 16) & 1u);
    return (u16)(r >> 16);
}

__device__ __forceinline__ f32x4 mfma16(bf16x8 a, bf16x8 b, f32x4 c) {
    return __builtin_amdgcn_mfma_f32_16x16x32_bf16(a, b, c, 0, 0, 0);
}

// ---------------------------------------------------------------------------
// GEMM1: C = X @ W^T + bias, X fp32 [4096,1024], W fp32 [1024,1024] (row = out col)
// Output: bf16 scattered to [B, H, S, DK]
// z: 0->Q, 1->K, 2->V
// ---------------------------------------------------------------------------
__global__ __launch_bounds__(256) void gemm_qkv(
    const float* __restrict__ q, const float* __restrict__ k, const float* __restrict__ v,
    const float* __restrict__ wq, const float* __restrict__ wk, const float* __restrict__ wv,
    const float* __restrict__ bq, const float* __restrict__ bk, const float* __restrict__ bv,
    u16* __restrict__ Qp, u16* __restrict__ Kp, u16* __restrict__ Vp)
{
    const int z = blockIdx.z;
    const float* X    = (z == 0) ? q  : (z == 1) ? k  : v;
    const float* W    = (z == 0) ? wq : (z == 1) ? wk : wv;
    const float* bias = (z == 0) ? bq : (z == 1) ? bk : bv;
    u16* out          = (z == 0) ? Qp : (z == 1) ? Kp : Vp;

    __shared__ u16 As[128 * 40];
    __shared__ u16 Bs[128 * 40];

    const int tid = threadIdx.x;
    const int bm = blockIdx.y * 128;
    const int bn = blockIdx.x * 128;
    const int lane = tid & 63, wave = tid >> 6;
    const int wm = (wave >> 1) * 64, wn = (wave & 1) * 64;
    const int r = lane & 15, qd = lane >> 4;

    f32x4 acc[4][4];
    #pragma unroll
    for (int i = 0; i < 4; ++i)
        #pragma unroll
        for (int j = 0; j < 4; ++j)
            acc[i][j] = (f32x4){0.f, 0.f, 0.f, 0.f};

    for (int kk = 0; kk < 1024; kk += 32) {
        __syncthreads();
        // stage A (fp32 -> bf16), 128x32 tile, 4 rounds
        #pragma unroll
        for (int rr = 0; rr < 4; ++rr) {
            int e = (rr * 256 + tid) * 4;
            int row = e >> 5, col = e & 31;
            float4 f = *(const float4*)(X + (size_t)(bm + row) * 1024 + kk + col);
            ushort4 u;
            u.x = f2bf(f.x); u.y = f2bf(f.y); u.z = f2bf(f.z); u.w = f2bf(f.w);
            *(ushort4*)(As + row * 40 + col) = u;
        }
        // stage B (fp32 -> bf16)
        #pragma unroll
        for (int rr = 0; rr < 4; ++rr) {
            int e = (rr * 256 + tid) * 4;
            int row = e >> 5, col = e & 31;
            float4 f = *(const float4*)(W + (size_t)(bn + row) * 1024 + kk + col);
            ushort4 u;
            u.x = f2bf(f.x); u.y = f2bf(f.y); u.z = f2bf(f.z); u.w = f2bf(f.w);
            *(ushort4*)(Bs + row * 40 + col) = u;
        }
        __syncthreads();

        bf16x8 aF[4], bF[4];
        #pragma unroll
        for (int i = 0; i < 4; ++i)
            aF[i] = *(const bf16x8*)(As + (wm + i * 16 + r) * 40 + qd * 8);
        #pragma unroll
        for (int j = 0; j < 4; ++j)
            bF[j] = *(const bf16x8*)(Bs + (wn + j * 16 + r) * 40 + qd * 8);
        #pragma unroll
        for (int i = 0; i < 4; ++i)
            #pragma unroll
            for (int j = 0; j < 4; ++j)
                acc[i][j] = mfma16(aF[i], bF[j], acc[i][j]);
    }

    // epilogue: scatter to [B,H,S,DK] bf16 with bias
    #pragma unroll
    for (int j = 0; j < 4; ++j) {
        int n = bn + wn + j * 16 + r;
        float bvl = bias[n];
        int h = n >> 6, d = n & 63;
        #pragma unroll
        for (int i = 0; i < 4; ++i) {
            #pragma unroll
            for (int reg = 0; reg < 4; ++reg) {
                int m = bm + wm + i * 16 + qd * 4 + reg;
                int b_ = m >> 11, s_ = m & 2047;
                out[(((size_t)b_ * HEADS + h) * SEQ + s_) * DK + d] =
                    f2bf(acc[i][j][reg] + bvl);
            }
        }
    }
}

// ---------------------------------------------------------------------------
// Flash attention: 1 block per (q-tile of 64 rows, b*h). Causal.
// Qp/Kp/Vp: bf16 [B,H,S,DK]; AO: bf16 [4096, 1024] (row-major, col = h*64+d)
// ---------------------------------------------------------------------------
__global__ __launch_bounds__(256) void attn_kernel(
    const u16* __restrict__ Qp, const u16* __restrict__ Kp,
    const u16* __restrict__ Vp, u16* __restrict__ AO)
{
    __shared__ u16 Kl[64 * 72];
    __shared__ u16 Vt[64 * 72];   // transposed: [dim][key]
    __shared__ u16 Pl[4 * 16 * 72];

    const int tid = threadIdx.x;
    const int t = blockIdx.x;        // q tile (64 rows)
    const int bh = blockIdx.y;       // b*16 + h
    const int b_ = bh >> 4, h = bh & 15;

    const u16* Qb = Qp + (size_t)bh * SEQ * DK;
    const u16* Kb = Kp + (size_t)bh * SEQ * DK;
    const u16* Vb = Vp + (size_t)bh * SEQ * DK;

    const int lane = tid & 63, w = tid >> 6;
    const int r = lane & 15, qd = lane >> 4;

    const int qrow = t * 64 + w * 16 + r;
    const bf16x8 aQ0 = *(const bf16x8*)(Qb + (size_t)qrow * 64 + qd * 8);
    const bf16x8 aQ1 = *(const bf16x8*)(Qb + (size_t)qrow * 64 + 32 + qd * 8);

    f32x4 o[4];
    #pragma unroll
    for (int i = 0; i < 4; ++i) o[i] = (f32x4){0.f, 0.f, 0.f, 0.f};
    float m_i[4] = {-1e30f, -1e30f, -1e30f, -1e30f};
    float l_i[4] = {0.f, 0.f, 0.f, 0.f};

    for (int j = 0; j <= t; ++j) {
        __syncthreads();
        // stage K tile and V^T tile (64 keys x 64 dims)
        #pragma unroll
        for (int rr = 0; rr < 2; ++rr) {
            int cidx = rr * 256 + tid;            // 512 chunks of 8 bf16
            int row = cidx >> 3, c8 = (cidx & 7) * 8;
            bf16x8 kv = *(const bf16x8*)(Kb + (size_t)(j * 64 + row) * 64 + c8);
            *(bf16x8*)(&Kl[row * 72 + c8]) = kv;
            bf16x8 vv = *(const bf16x8*)(Vb + (size_t)(j * 64 + row) * 64 + c8);
            u16* vp = (u16*)&vv;
            #pragma unroll
            for (int e2 = 0; e2 < 8; ++e2)
                Vt[(c8 + e2) * 72 + row] = vp[e2];
        }
        __syncthreads();

        // S = Q K^T * scale  (16 rows x 64 keys per wave)
        f32x4 sc[4];
        #pragma unroll
        for (int nb = 0; nb < 4; ++nb) {
            bf16x8 b0 = *(const bf16x8*)(&Kl[(nb * 16 + r) * 72 + qd * 8]);
            bf16x8 b1 = *(const bf16x8*)(&Kl[(nb * 16 + r) * 72 + 32 + qd * 8]);
            f32x4 s = (f32x4){0.f, 0.f, 0.f, 0.f};
            s = mfma16(aQ0, b0, s);
            s = mfma16(aQ1, b1, s);
            sc[nb] = s * 0.125f;   // 1/sqrt(64)
        }
        if (j == t) {   // causal mask within diagonal tile
            #pragma unroll
            for (int nb = 0; nb < 4; ++nb) {
                int col = nb * 16 + r;
                #pragma unroll
                for (int reg = 0; reg < 4; ++reg) {
                    int rowq = w * 16 + qd * 4 + reg;
                    if (col > rowq) sc[nb][reg] = -1e30f;
                }
            }
        }

        // online softmax
        float alpha[4];
        #pragma unroll
        for (int reg = 0; reg < 4; ++reg) {
            float mx = fmaxf(fmaxf(sc[0][reg], sc[1][reg]), fmaxf(sc[2][reg], sc[3][reg]));
            #pragma unroll
            for (int d2 = 1; d2 < 16; d2 <<= 1) mx = fmaxf(mx, __shfl_xor(mx, d2));
            float mnew = fmaxf(m_i[reg], mx);
            alpha[reg] = __expf(m_i[reg] - mnew);
            m_i[reg] = mnew;
            float rs = 0.f;
            #pragma unroll
            for (int nb = 0; nb < 4; ++nb) {
                float p = __expf(sc[nb][reg] - mnew);
                sc[nb][reg] = p;
                rs += p;
            }
            #pragma unroll
            for (int d2 = 1; d2 < 16; d2 <<= 1) rs += __shfl_xor(rs, d2);
            l_i[reg] = l_i[reg] * alpha[reg] + rs;
            #pragma unroll
            for (int db = 0; db < 4; ++db) o[db][reg] *= alpha[reg];
        }

        // P -> LDS (C-layout positions, read back in A-layout)
        #pragma unroll
        for (int nb = 0; nb < 4; ++nb)
            #pragma unroll
            for (int reg = 0; reg < 4; ++reg)
                Pl[w * 1152 + (qd * 4 + reg) * 72 + nb * 16 + r] = f2bf(sc[nb][reg]);
        __syncthreads();

        // O += P @ V
        bf16x8 aP0 = *(const bf16x8*)(&Pl[w * 1152 + r * 72 + qd * 8]);
        bf16x8 aP1 = *(const bf16x8*)(&Pl[w * 1152 + r * 72 + 32 + qd * 8]);
        #pragma unroll
        for (int db = 0; db < 4; ++db) {
            bf16x8 bV0 = *(const bf16x8*)(&Vt[(db * 16 + r) * 72 + qd * 8]);
            bf16x8 bV1 = *(const bf16x8*)(&Vt[(db * 16 + r) * 72 + 32 + qd * 8]);
            o[db] = mfma16(aP0, bV0, o[db]);
            o[db] = mfma16(aP1, bV1, o[db]);
        }
    }

    // epilogue: O / l -> AO bf16 [4096, 1024]
    #pragma unroll
    for (int db = 0; db < 4; ++db) {
        #pragma unroll
        for (int reg = 0; reg < 4; ++reg) {
            int rowq = t * 64 + w * 16 + qd * 4 + reg;
            float ov = o[db][reg] / l_i[reg];
            AO[((size_t)(b_ * SEQ + rowq)) * D_MODEL + h * 64 + db * 16 + r] = f2bf(ov);
        }
    }
}

// ---------------------------------------------------------------------------
// GEMM2: out = AO @ Wo^T + bo, AO bf16 [4096,1024], Wo fp32 [1024,1024], out fp32
// ---------------------------------------------------------------------------
__global__ __launch_bounds__(256) void gemm_out(
    const u16* __restrict__ AO, const float* __restrict__ W,
    const float* __restrict__ bias, float* __restrict__ out)
{
    __shared__ u16 As[128 * 40];
    __shared__ u16 Bs[128 * 40];

    const int tid = threadIdx.x;
    const int bm = blockIdx.y * 128;
    const int bn = blockIdx.x * 128;
    const int lane = tid & 63, wave = tid >> 6;
    const int wm = (wave >> 1) * 64, wn = (wave & 1) * 64;
    const int r = lane & 15, qd = lane >> 4;

    f32x4 acc[4][4];
    #pragma unroll
    for (int i = 0; i < 4; ++i)
        #pragma unroll
        for (int j = 0; j < 4; ++j)
            acc[i][j] = (f32x4){0.f, 0.f, 0.f, 0.f};

    for (int kk = 0; kk < 1024; kk += 32) {
        __syncthreads();
        // stage A (bf16 direct), 2 rounds of 16B
        #pragma unroll
        for (int rr = 0; rr < 2; ++rr) {
            int e = (rr * 256 + tid) * 8;
            int row = e >> 5, col = e & 31;
            bf16x8 val = *(const bf16x8*)(AO + (size_t)(bm + row) * 1024 + kk + col);
            *(bf16x8*)(As + row * 40 + col) = val;
        }
        // stage B (fp32 -> bf16), 4 rounds
        #pragma unroll
        for (int rr = 0; rr < 4; ++rr) {
            int e = (rr * 256 + tid) * 4;
            int row = e >> 5, col = e & 31;
            float4 f = *(const float4*)(W + (size_t)(bn + row) * 1024 + kk + col);
            ushort4 u;
            u.x = f2bf(f.x); u.y = f2bf(f.y); u.z = f2bf(f.z); u.w = f2bf(f.w);
            *(ushort4*)(Bs + row * 40 + col) = u;
        }
        __syncthreads();

        bf16x8 aF[4], bF[4];
        #pragma unroll
        for (int i = 0; i < 4; ++i)
            aF[i] = *(const bf16x8*)(As + (wm + i * 16 + r) * 40 + qd * 8);
        #pragma unroll
        for (int j = 0; j < 4; ++j)
            bF[j] = *(const bf16x8*)(Bs + (wn + j * 16 + r) * 40 + qd * 8);
        #pragma unroll
        for (int i = 0; i < 4; ++i)
            #pragma unroll
            for (int j = 0; j < 4; ++j)
                acc[i][j] = mfma16(aF[i], bF[j], acc[i][j]);
    }

    #pragma unroll
    for (int j = 0; j < 4; ++j) {
        int n = bn + wn + j * 16 + r;
        float bvl = bias[n];
        #pragma unroll
        for (int i = 0; i < 4; ++i) {
            #pragma unroll
            for (int reg = 0; reg < 4; ++reg) {
                int m = bm + wm + i * 16 + qd * 4 + reg;
                out[(size_t)m * 1024 + n] = acc[i][j][reg] + bvl;
            }
        }
    }
}

// ---------------------------------------------------------------------------
extern "C" void kernel_launch(void* const* d_in, const int* in_sizes, int n_in,
                              void* d_out, int out_size, void* d_ws, size_t ws_size,
                              hipStream_t stream) {
    const float* q  = (const float*)d_in[0];
    const float* k  = (const float*)d_in[1];
    const float* v  = (const float*)d_in[2];
    // d_in[3] = mask (causal tril) — hardcoded in attn kernel
    const float* wq = (const float*)d_in[4];
    const float* bq = (const float*)d_in[5];
    const float* wk = (const float*)d_in[6];
    const float* bk = (const float*)d_in[7];
    const float* wv = (const float*)d_in[8];
    const float* bv = (const float*)d_in[9];
    const float* wo = (const float*)d_in[10];
    const float* bo = (const float*)d_in[11];
    float* out = (float*)d_out;

    u16* Qp = (u16*)d_ws;                      // [B,H,S,DK] bf16
    u16* Kp = Qp + (size_t)4 * 1024 * 1024;
    u16* Vp = Kp + (size_t)4 * 1024 * 1024;
    u16* AO = Vp + (size_t)4 * 1024 * 1024;    // [4096,1024] bf16

    gemm_qkv<<<dim3(8, 32, 3), 256, 0, stream>>>(q, k, v, wq, wk, wv, bq, bk, bv, Qp, Kp, Vp);
    attn_kernel<<<dim3(32, 32), 256, 0, stream>>>(Qp, Kp, Vp, AO);
    gemm_out<<<dim3(8, 32), 256, 0, stream>>>(AO, wo, bo, out);
}

// Round 2
// 332.011 us; speedup vs baseline: 1.2774x; 1.2774x over previous
//
#include <hip/hip_runtime.h>

typedef unsigned short u16;
typedef __attribute__((ext_vector_type(8))) short bf16x8;
typedef __attribute__((ext_vector_type(4))) float f32x4;

#define SEQ 2048
#define DMODEL 1024

__device__ __forceinline__ u16 f2bf(float f) {
    union { float f; unsigned u; } x; x.f = f;
    unsigned r = x.u + 0x7fffu + ((x.u >> 16) & 1u);
    return (u16)(r >> 16);
}

__device__ __forceinline__ f32x4 mfma16(bf16x8 a, bf16x8 b, f32x4 c) {
    return __builtin_amdgcn_mfma_f32_16x16x32_bf16(a, b, c, 0, 0, 0);
}

// async global->LDS, 16B per lane; lds ptr must be wave-uniform (HW adds lane*16)
__device__ __forceinline__ void gld16(const u16* g, u16* l) {
    __builtin_amdgcn_global_load_lds(
        (__attribute__((address_space(1))) const void*)g,
        (__attribute__((address_space(3))) void*)l, 16, 0, 0);
}

// ---------------------------------------------------------------------------
// fp32 -> bf16 conversion for the 7 fp32 operands (q,k,v,wq,wk,wv,wo)
// ---------------------------------------------------------------------------
struct CvtArgs {
    const float* src[7];
    u16* dst[7];
    int n4[7];        // element count / 4
};

__global__ __launch_bounds__(256) void cvt_kernel(CvtArgs a) {
    const int id = blockIdx.y;
    const int i = blockIdx.x * 256 + threadIdx.x;
    if (i >= a.n4[id]) return;
    float4 f = ((const float4*)a.src[id])[i];
    ushort4 u;
    u.x = f2bf(f.x); u.y = f2bf(f.y); u.z = f2bf(f.z); u.w = f2bf(f.w);
    ((ushort4*)a.dst[id])[i] = u;
}

// ---------------------------------------------------------------------------
// GEMM (m97-style): C = X @ W^T + bias. X bf16 [4096,1024], W bf16 [1024,1024].
// 128x128 tile, BK=32, global_load_lds width-16 staging.
// z: 0 -> Q as [4096,1024]; 1 -> K as [B,H,S,DK]; 2 -> V^T as [B,H,DK,S]
// ---------------------------------------------------------------------------
__global__ __launch_bounds__(256) void gemm_qkv(
    const u16* __restrict__ Xq, const u16* __restrict__ Xk, const u16* __restrict__ Xv,
    const u16* __restrict__ Wq, const u16* __restrict__ Wk, const u16* __restrict__ Wv,
    const float* __restrict__ bq, const float* __restrict__ bk, const float* __restrict__ bv,
    u16* __restrict__ Qb, u16* __restrict__ Kb, u16* __restrict__ Vb)
{
    const int z = blockIdx.z;
    const u16* X = (z == 0) ? Xq : (z == 1) ? Xk : Xv;
    const u16* W = (z == 0) ? Wq : (z == 1) ? Wk : Wv;
    const float* bias = (z == 0) ? bq : (z == 1) ? bk : bv;

    __shared__ u16 As[128 * 32];
    __shared__ u16 Bs[128 * 32];

    const int tid = threadIdx.x;
    const int bm = blockIdx.y * 128, bn = blockIdx.x * 128;
    const int lane = tid & 63, w = tid >> 6;
    const int wm = (w >> 1) * 64, wn = (w & 1) * 64;
    const int r = lane & 15, qd = lane >> 4;

    // staging chunk ids: 512 chunks of 16B per tile, 2 per thread
    const int cb0 = w * 64;            // wave-uniform chunk bases
    const int cb1 = 256 + w * 64;
    const int c0 = cb0 + lane, c1 = cb1 + lane;
    const int r0 = c0 >> 2, o0 = (c0 & 3) * 8;
    const int r1 = c1 >> 2, o1 = (c1 & 3) * 8;

    f32x4 acc[4][4];
    #pragma unroll
    for (int i = 0; i < 4; ++i)
        #pragma unroll
        for (int j = 0; j < 4; ++j)
            acc[i][j] = (f32x4){0.f, 0.f, 0.f, 0.f};

    for (int kk = 0; kk < 1024; kk += 32) {
        __syncthreads();
        gld16(X + (size_t)(bm + r0) * 1024 + kk + o0, As + cb0 * 8);
        gld16(X + (size_t)(bm + r1) * 1024 + kk + o1, As + cb1 * 8);
        gld16(W + (size_t)(bn + r0) * 1024 + kk + o0, Bs + cb0 * 8);
        gld16(W + (size_t)(bn + r1) * 1024 + kk + o1, Bs + cb1 * 8);
        __syncthreads();

        bf16x8 aF[4], bF[4];
        #pragma unroll
        for (int i = 0; i < 4; ++i)
            aF[i] = *(const bf16x8*)(As + (wm + i * 16 + r) * 32 + qd * 8);
        #pragma unroll
        for (int j = 0; j < 4; ++j)
            bF[j] = *(const bf16x8*)(Bs + (wn + j * 16 + r) * 32 + qd * 8);
        #pragma unroll
        for (int i = 0; i < 4; ++i)
            #pragma unroll
            for (int j = 0; j < 4; ++j)
                acc[i][j] = mfma16(aF[i], bF[j], acc[i][j]);
    }

    #pragma unroll
    for (int j = 0; j < 4; ++j) {
        const int n = bn + wn + j * 16 + r;
        const float bvl = bias[n];
        const int h = n >> 6, d = n & 63;
        #pragma unroll
        for (int i = 0; i < 4; ++i) {
            const int m0 = bm + wm + i * 16 + qd * 4;
            const int b_ = m0 >> 11, s0 = m0 & 2047;
            if (z == 0) {
                #pragma unroll
                for (int reg = 0; reg < 4; ++reg)
                    Qb[(size_t)(m0 + reg) * 1024 + n] = f2bf(acc[i][j][reg] + bvl);
            } else if (z == 1) {
                #pragma unroll
                for (int reg = 0; reg < 4; ++reg)
                    Kb[((size_t)(b_ * 16 + h) * SEQ + s0 + reg) * 64 + d] =
                        f2bf(acc[i][j][reg] + bvl);
            } else {
                ushort4 u;
                u.x = f2bf(acc[i][j][0] + bvl);
                u.y = f2bf(acc[i][j][1] + bvl);
                u.z = f2bf(acc[i][j][2] + bvl);
                u.w = f2bf(acc[i][j][3] + bvl);
                *(ushort4*)(Vb + ((size_t)(b_ * 16 + h) * 64 + d) * SEQ + s0) = u;
            }
        }
    }
}

// ---------------------------------------------------------------------------
// Barrier-free flash attention. One wave = 16 Q-rows; wave handles q-subtiles
// (u, 127-u) -> every wave does 33-34 K-tiles of 64 keys. K/V fragments loaded
// directly from global (L2-resident); only P round-trips per-wave LDS.
// ---------------------------------------------------------------------------
__global__ __launch_bounds__(256) void attn_kernel(
    const u16* __restrict__ Qb, const u16* __restrict__ Kb,
    const u16* __restrict__ Vb, u16* __restrict__ AO)
{
    __shared__ u16 Pl[4 * 16 * 72];   // per-wave 16x72 patch, no barriers needed

    const int tid = threadIdx.x;
    const int lane = tid & 63, w = tid >> 6;
    const int g = blockIdx.x * 4 + w;      // 0..2047
    const int bh = g >> 6, u = g & 63;     // waves in a block share bh (L2/L1 locality)
    const int b_ = bh >> 4, h = bh & 15;
    const int r = lane & 15, qd = lane >> 4;
    u16* P = Pl + w * 1152;

    const u16* Kh = Kb + (size_t)bh * SEQ * 64;
    const u16* Vh = Vb + (size_t)bh * 64 * SEQ;

    for (int half = 0; half < 2; ++half) {
        const int t = half ? (127 - u) : u;

        const size_t qoff = (size_t)(b_ * SEQ + t * 16 + r) * DMODEL + h * 64;
        const bf16x8 aQ0 = *(const bf16x8*)(Qb + qoff + qd * 8);
        const bf16x8 aQ1 = *(const bf16x8*)(Qb + qoff + 32 + qd * 8);

        f32x4 o[4];
        float m_i[4], l_i[4];
        #pragma unroll
        for (int i = 0; i < 4; ++i) {
            o[i] = (f32x4){0.f, 0.f, 0.f, 0.f};
            m_i[i] = -1e30f; l_i[i] = 0.f;
        }

        const int jmax = t >> 2;
        for (int j = 0; j <= jmax; ++j) {
            const u16* Kt = Kh + (size_t)j * 64 * 64;
            const u16* Vt = Vh + j * 64;

            bf16x8 kf[4][2], vf[4][2];
            #pragma unroll
            for (int nb = 0; nb < 4; ++nb) {
                kf[nb][0] = *(const bf16x8*)(Kt + (nb * 16 + r) * 64 + qd * 8);
                kf[nb][1] = *(const bf16x8*)(Kt + (nb * 16 + r) * 64 + 32 + qd * 8);
            }
            #pragma unroll
            for (int db = 0; db < 4; ++db) {
                vf[db][0] = *(const bf16x8*)(Vt + (size_t)(db * 16 + r) * SEQ + qd * 8);
                vf[db][1] = *(const bf16x8*)(Vt + (size_t)(db * 16 + r) * SEQ + 32 + qd * 8);
            }

            f32x4 sc[4];
            #pragma unroll
            for (int nb = 0; nb < 4; ++nb) {
                f32x4 s = (f32x4){0.f, 0.f, 0.f, 0.f};
                s = mfma16(aQ0, kf[nb][0], s);
                s = mfma16(aQ1, kf[nb][1], s);
                sc[nb] = s * 0.125f;   // 1/sqrt(64)
            }

            if (j == jmax) {           // causal mask: only final tile can clip
                #pragma unroll
                for (int nb = 0; nb < 4; ++nb) {
                    const int col = j * 64 + nb * 16 + r;
                    #pragma unroll
                    for (int reg = 0; reg < 4; ++reg) {
                        const int row = t * 16 + qd * 4 + reg;
                        if (col > row) sc[nb][reg] = -1e30f;
                    }
                }
            }

            // online softmax (row = qd*4+reg, cols spread over 16 lanes x 4 nb)
            #pragma unroll
            for (int reg = 0; reg < 4; ++reg) {
                float mx = fmaxf(fmaxf(sc[0][reg], sc[1][reg]),
                                 fmaxf(sc[2][reg], sc[3][reg]));
                #pragma unroll
                for (int d2 = 1; d2 < 16; d2 <<= 1) mx = fmaxf(mx, __shfl_xor(mx, d2));
                const float mnew = fmaxf(m_i[reg], mx);
                const float alpha = __expf(m_i[reg] - mnew);
                m_i[reg] = mnew;
                float rs = 0.f;
                #pragma unroll
                for (int nb = 0; nb < 4; ++nb) {
                    const float p = __expf(sc[nb][reg] - mnew);
                    sc[nb][reg] = p;
                    rs += p;
                }
                #pragma unroll
                for (int d2 = 1; d2 < 16; d2 <<= 1) rs += __shfl_xor(rs, d2);
                l_i[reg] = l_i[reg] * alpha + rs;
                #pragma unroll
                for (int db = 0; db < 4; ++db) o[db][reg] *= alpha;
            }

            // P: C-layout -> LDS -> A-layout (per-wave, ordered by lgkmcnt)
            #pragma unroll
            for (int nb = 0; nb < 4; ++nb)
                #pragma unroll
                for (int reg = 0; reg < 4; ++reg)
                    P[(qd * 4 + reg) * 72 + nb * 16 + r] = f2bf(sc[nb][reg]);

            const bf16x8 aP0 = *(const bf16x8*)(P + r * 72 + qd * 8);
            const bf16x8 aP1 = *(const bf16x8*)(P + r * 72 + 32 + qd * 8);
            #pragma unroll
            for (int db = 0; db < 4; ++db) {
                o[db] = mfma16(aP0, vf[db][0], o[db]);
                o[db] = mfma16(aP1, vf[db][1], o[db]);
            }
        }

        #pragma unroll
        for (int db = 0; db < 4; ++db)
            #pragma unroll
            for (int reg = 0; reg < 4; ++reg) {
                const int row = t * 16 + qd * 4 + reg;
                AO[(size_t)(b_ * SEQ + row) * DMODEL + h * 64 + db * 16 + r] =
                    f2bf(o[db][reg] / l_i[reg]);
            }
    }
}

// ---------------------------------------------------------------------------
// GEMM2: out = AO @ Wo^T + bo (fp32 out)
// ---------------------------------------------------------------------------
__global__ __launch_bounds__(256) void gemm_out(
    const u16* __restrict__ AO, const u16* __restrict__ W,
    const float* __restrict__ bias, float* __restrict__ out)
{
    __shared__ u16 As[128 * 32];
    __shared__ u16 Bs[128 * 32];

    const int tid = threadIdx.x;
    const int bm = blockIdx.y * 128, bn = blockIdx.x * 128;
    const int lane = tid & 63, w = tid >> 6;
    const int wm = (w >> 1) * 64, wn = (w & 1) * 64;
    const int r = lane & 15, qd = lane >> 4;

    const int cb0 = w * 64;
    const int cb1 = 256 + w * 64;
    const int c0 = cb0 + lane, c1 = cb1 + lane;
    const int r0 = c0 >> 2, o0 = (c0 & 3) * 8;
    const int r1 = c1 >> 2, o1 = (c1 & 3) * 8;

    f32x4 acc[4][4];
    #pragma unroll
    for (int i = 0; i < 4; ++i)
        #pragma unroll
        for (int j = 0; j < 4; ++j)
            acc[i][j] = (f32x4){0.f, 0.f, 0.f, 0.f};

    for (int kk = 0; kk < 1024; kk += 32) {
        __syncthreads();
        gld16(AO + (size_t)(bm + r0) * 1024 + kk + o0, As + cb0 * 8);
        gld16(AO + (size_t)(bm + r1) * 1024 + kk + o1, As + cb1 * 8);
        gld16(W + (size_t)(bn + r0) * 1024 + kk + o0, Bs + cb0 * 8);
        gld16(W + (size_t)(bn + r1) * 1024 + kk + o1, Bs + cb1 * 8);
        __syncthreads();

        bf16x8 aF[4], bF[4];
        #pragma unroll
        for (int i = 0; i < 4; ++i)
            aF[i] = *(const bf16x8*)(As + (wm + i * 16 + r) * 32 + qd * 8);
        #pragma unroll
        for (int j = 0; j < 4; ++j)
            bF[j] = *(const bf16x8*)(Bs + (wn + j * 16 + r) * 32 + qd * 8);
        #pragma unroll
        for (int i = 0; i < 4; ++i)
            #pragma unroll
            for (int j = 0; j < 4; ++j)
                acc[i][j] = mfma16(aF[i], bF[j], acc[i][j]);
    }

    #pragma unroll
    for (int j = 0; j < 4; ++j) {
        const int n = bn + wn + j * 16 + r;
        const float bvl = bias[n];
        #pragma unroll
        for (int i = 0; i < 4; ++i) {
            const int m0 = bm + wm + i * 16 + qd * 4;
            #pragma unroll
            for (int reg = 0; reg < 4; ++reg)
                out[(size_t)(m0 + reg) * 1024 + n] = acc[i][j][reg] + bvl;
        }
    }
}

// ---------------------------------------------------------------------------
extern "C" void kernel_launch(void* const* d_in, const int* in_sizes, int n_in,
                              void* d_out, int out_size, void* d_ws, size_t ws_size,
                              hipStream_t stream) {
    const float* q  = (const float*)d_in[0];
    const float* k  = (const float*)d_in[1];
    const float* v  = (const float*)d_in[2];
    // d_in[3] = causal mask, hardcoded
    const float* wq = (const float*)d_in[4];
    const float* bq = (const float*)d_in[5];
    const float* wk = (const float*)d_in[6];
    const float* bk = (const float*)d_in[7];
    const float* wv = (const float*)d_in[8];
    const float* bv = (const float*)d_in[9];
    const float* wo = (const float*)d_in[10];
    const float* bo = (const float*)d_in[11];
    float* out = (float*)d_out;

    u16* ws = (u16*)d_ws;
    u16* Xq = ws;                       // [4096,1024] bf16 inputs
    u16* Xk = Xq + (size_t)4194304;
    u16* Xv = Xk + (size_t)4194304;
    u16* Wq = Xv + (size_t)4194304;     // [1024,1024] bf16 weights
    u16* Wk = Wq + (size_t)1048576;
    u16* Wv = Wk + (size_t)1048576;
    u16* Wo = Wv + (size_t)1048576;
    u16* Qb = Wo + (size_t)1048576;     // [4096,1024]
    u16* Kb = Qb + (size_t)4194304;     // [B,H,S,DK]
    u16* Vb = Kb + (size_t)4194304;     // [B,H,DK,S]
    u16* AO = Vb + (size_t)4194304;     // [4096,1024]
    // total 64 MB

    CvtArgs ca;
    ca.src[0] = q;  ca.dst[0] = Xq; ca.n4[0] = 1048576;
    ca.src[1] = k;  ca.dst[1] = Xk; ca.n4[1] = 1048576;
    ca.src[2] = v;  ca.dst[2] = Xv; ca.n4[2] = 1048576;
    ca.src[3] = wq; ca.dst[3] = Wq; ca.n4[3] = 262144;
    ca.src[4] = wk; ca.dst[4] = Wk; ca.n4[4] = 262144;
    ca.src[5] = wv; ca.dst[5] = Wv; ca.n4[5] = 262144;
    ca.src[6] = wo; ca.dst[6] = Wo; ca.n4[6] = 262144;

    cvt_kernel<<<dim3(4096, 7), 256, 0, stream>>>(ca);
    gemm_qkv<<<dim3(8, 32, 3), 256, 0, stream>>>(Xq, Xk, Xv, Wq, Wk, Wv,
                                                 bq, bk, bv, Qb, Kb, Vb);
    attn_kernel<<<dim3(512), 256, 0, stream>>>(Qb, Kb, Vb, AO);
    gemm_out<<<dim3(8, 32), 256, 0, stream>>>(AO, Wo, bo, out);
}